// Round 5
// baseline (148.370 us; speedup 1.0000x reference)
//
#include <hip/hip_runtime.h>

#define THREADS 1024
#define HW 16384        // H*W per (b,c) row
#define K_SEL 8192u     // k = 0.5 * H * W
#define NB1 2048        // pass-1: abs bits [30:20]
#define NB2 1024        // pass-2: bits [19:10]
#define NB3 1024        // pass-3: bits [9:0]
#define VPT 4           // uint4 per thread per row (THREADS*VPT*4 == HW)
#define RPB 16          // rows per block
#define LDS_WORDS (HW + NB1 + NB2 + NB3)   // 20480 words = 81920 B

static_assert(THREADS * VPT * 4 == HW, "row tiling");

// Barrier that waits LDS ops only — does NOT drain vmcnt, so async global->LDS
// DMA and in-flight global stores keep flying across it.
__device__ __forceinline__ void lgk_barrier() {
  asm volatile("s_waitcnt lgkmcnt(0)" ::: "memory");
  __builtin_amdgcn_s_barrier();
}

// Issue one row (64 KB) global->LDS async. 64 chunks of 1 KB; 4 per wave.
// LDS dest is wave-uniform base (HW adds lane*16); global src is per-lane.
__device__ __forceinline__ void dma_row(const unsigned* __restrict__ gsrc,
                                        unsigned* lds, int wid, int lane) {
#pragma unroll
  for (int i = 0; i < 4; ++i) {
    const int chunk = wid * 4 + i;
    __builtin_amdgcn_global_load_lds(
        (const __attribute__((address_space(1))) unsigned*)(gsrc + chunk * 256 + lane * 4),
        (__attribute__((address_space(3))) unsigned*)(lds + chunk * 256),
        16, 0, 0);
  }
}

__device__ __forceinline__ void reload(uint4 (&v)[VPT], const uint4* __restrict__ data4, int t) {
#pragma unroll
  for (int i = 0; i < VPT; ++i) v[i] = data4[i * THREADS + t];
}

// All-wave redundant bin search (identical result in every wave's registers;
// no broadcast, no extra barrier). Bins ascend in value; returns the bin
// holding the kRem-th LARGEST element and the residual rank within it.
template <int NBINS>
__device__ __forceinline__ void find_bin(const unsigned* __restrict__ hist,
                                         unsigned kRem, unsigned& bin, unsigned& krem) {
  constexpr int bpl = NBINS >> 6;             // bins per lane
  const int lane = (int)(threadIdx.x & 63);
  const int base = lane * bpl;
  unsigned s = 0;
#pragma unroll
  for (int j = 0; j < bpl; ++j) s += hist[base + ((j + lane) & (bpl - 1))];
  unsigned suf = s;                            // inclusive suffix sum over lanes
#pragma unroll
  for (int off = 1; off < 64; off <<= 1) {
    unsigned w = __shfl_down(suf, off);
    if (lane + off < 64) suf += w;
  }
  const unsigned cumAbove = suf - s;
  const bool hit = (cumAbove < kRem) && (kRem <= suf);
  const unsigned long long m = __ballot(hit);
  const int tl = (int)__builtin_ctzll(m);
  const unsigned cumTl = __shfl(cumAbove, tl);
  // Within-chunk suffix scan, done redundantly by every bpl-lane group.
  const int j = lane & (bpl - 1);
  const unsigned h = hist[tl * bpl + j];
  unsigned sufc = h;
#pragma unroll
  for (int off = 1; off < 32; off <<= 1) {
    if (off < bpl) {
      unsigned w = __shfl_down(sufc, off);
      if (j + off < bpl) sufc += w;
    }
  }
  const unsigned cumW = sufc - h;
  const bool hit2 = ((cumTl + cumW) < kRem) && (kRem <= cumTl + cumW + h);
  const unsigned long long m2 = __ballot(hit2);
  const int jl = (int)__builtin_ctzll(m2) & (bpl - 1);
  bin = (unsigned)(tl * bpl + jl);
  krem = kRem - cumTl - __shfl(cumW, jl);
}

// 3-pass exact radix select (11/10/10 bits of |x|) + masked store, all from
// registers. 3 lgk-only barriers; vmcnt untouched. Hist zero-folding:
// P1 zeros h2, P2 zeros h3, P3 zeros h1 (each dead since its last find).
__device__ __forceinline__ void select_store(const uint4 (&v)[VPT],
                                             unsigned* h1, unsigned* h2, unsigned* h3,
                                             uint4* __restrict__ dstRow, int t) {
  // P1: bits [30:20] -> h1
#pragma unroll
  for (int i = 0; i < VPT; ++i) {
    atomicAdd(&h1[(v[i].x & 0x7fffffffu) >> 20], 1u);
    atomicAdd(&h1[(v[i].y & 0x7fffffffu) >> 20], 1u);
    atomicAdd(&h1[(v[i].z & 0x7fffffffu) >> 20], 1u);
    atomicAdd(&h1[(v[i].w & 0x7fffffffu) >> 20], 1u);
  }
  h2[t] = 0;
  lgk_barrier();
  unsigned T1, kRem;
  find_bin<NB1>(h1, K_SEL, T1, kRem);

  // P2: among (a>>20)==T1, bits [19:10] -> h2
#pragma unroll
  for (int i = 0; i < VPT; ++i) {
    unsigned a;
    a = v[i].x & 0x7fffffffu; if ((a >> 20) == T1) atomicAdd(&h2[(a >> 10) & (NB2 - 1)], 1u);
    a = v[i].y & 0x7fffffffu; if ((a >> 20) == T1) atomicAdd(&h2[(a >> 10) & (NB2 - 1)], 1u);
    a = v[i].z & 0x7fffffffu; if ((a >> 20) == T1) atomicAdd(&h2[(a >> 10) & (NB2 - 1)], 1u);
    a = v[i].w & 0x7fffffffu; if ((a >> 20) == T1) atomicAdd(&h2[(a >> 10) & (NB2 - 1)], 1u);
  }
  h3[t] = 0;
  lgk_barrier();
  unsigned b2;
  find_bin<NB2>(h2, kRem, b2, kRem);
  const unsigned pref2 = (T1 << 10) | b2;     // == a>>10 of threshold

  // P3: among (a>>10)==pref2, bits [9:0] -> h3
#pragma unroll
  for (int i = 0; i < VPT; ++i) {
    unsigned a;
    a = v[i].x & 0x7fffffffu; if ((a >> 10) == pref2) atomicAdd(&h3[a & (NB3 - 1)], 1u);
    a = v[i].y & 0x7fffffffu; if ((a >> 10) == pref2) atomicAdd(&h3[a & (NB3 - 1)], 1u);
    a = v[i].z & 0x7fffffffu; if ((a >> 10) == pref2) atomicAdd(&h3[a & (NB3 - 1)], 1u);
    a = v[i].w & 0x7fffffffu; if ((a >> 10) == pref2) atomicAdd(&h3[a & (NB3 - 1)], 1u);
  }
  h1[t] = 0; h1[t + THREADS] = 0;
  lgk_barrier();
  unsigned b3, kd;
  find_bin<NB3>(h3, kRem, b3, kd);
  const unsigned thr = (pref2 << 10) | b3;    // exact k-th largest |x| bits

  // Masked store (>= keeps ties, same as reference). 4 stores/thread.
#pragma unroll
  for (int i = 0; i < VPT; ++i) {
    uint4 w = v[i];
    w.x = ((w.x & 0x7fffffffu) >= thr) ? w.x : 0u;
    w.y = ((w.y & 0x7fffffffu) >= thr) ? w.y : 0u;
    w.z = ((w.z & 0x7fffffffu) >= thr) ? w.z : 0u;
    w.w = ((w.w & 0x7fffffffu) >= thr) ? w.w : 0u;
    dstRow[i * THREADS + t] = w;
  }
}

extern "C" __global__ __launch_bounds__(THREADS, 4)
void sparsify_topk_kernel(const float* __restrict__ x, float* __restrict__ out) {
  extern __shared__ __align__(16) unsigned smem[];
  unsigned* data = smem;                 // HW words: DMA landing buffer
  unsigned* h1 = smem + HW;              // NB1
  unsigned* h2 = h1 + NB1;               // NB2
  unsigned* h3 = h2 + NB2;               // NB3
  const uint4* data4 = (const uint4*)data;

  const int t = (int)threadIdx.x;
  const int lane = t & 63, wid = t >> 6;
  const size_t base = (size_t)blockIdx.x * RPB * HW;
  const unsigned* src = (const unsigned*)x + base;
  uint4* dst = (uint4*)out + base / 4;

  // Prologue: zero h1 (h2/h3 zeroed inside row 0's P1/P2); DMA row 0; drain;
  // pull row 0 to regs; free buffer; start DMA row 1.
  h1[t] = 0; h1[t + THREADS] = 0;
  dma_row(src, data, wid, lane);
  asm volatile("s_waitcnt vmcnt(0)" ::: "memory");
  lgk_barrier();

  uint4 vA[VPT], vB[VPT];
  reload(vA, data4, t);
  lgk_barrier();                         // all reloads done -> buffer free
  dma_row(src + HW, data, wid, lane);

  for (int r = 0; r < RPB; r += 2) {
    // ---- even row r: data in vA; DMA(r+1) in flight ----
    select_store(vA, h1, h2, h3, dst + (size_t)r * (HW / 4), t);
    // Outstanding per wave (oldest first): [stores r-1 (retired)], DMA(r+1):4,
    // stores(r):4. vmcnt(4) => DMA(r+1) landed; stores keep flying.
    asm volatile("s_waitcnt vmcnt(4)" ::: "memory");
    __builtin_amdgcn_s_barrier();
    reload(vB, data4, t);
    lgk_barrier();                       // buffer free
    if (r + 2 < RPB) dma_row(src + (size_t)(r + 2) * HW, data, wid, lane);

    // ---- odd row r+1: data in vB; DMA(r+2) in flight ----
    select_store(vB, h1, h2, h3, dst + (size_t)(r + 1) * (HW / 4), t);
    if (r + 2 < RPB) {
      asm volatile("s_waitcnt vmcnt(4)" ::: "memory");
      __builtin_amdgcn_s_barrier();
      reload(vA, data4, t);
      lgk_barrier();
      if (r + 3 < RPB) dma_row(src + (size_t)(r + 3) * HW, data, wid, lane);
    }
  }
}

extern "C" void kernel_launch(void* const* d_in, const int* in_sizes, int n_in,
                              void* d_out, int out_size, void* d_ws, size_t ws_size,
                              hipStream_t stream) {
  (void)n_in; (void)d_ws; (void)ws_size; (void)out_size;
  const float* x = (const float*)d_in[0];
  float* out = (float*)d_out;
  const int rows = in_sizes[0] / HW;           // 4096
  const int blocks = rows / RPB;               // 256
  const size_t shmem = (size_t)LDS_WORDS * sizeof(unsigned);  // 81,920 B
  sparsify_topk_kernel<<<dim3(blocks), dim3(THREADS), shmem, stream>>>(x, out);
}

// Round 7
// 115.192 us; speedup vs baseline: 1.2880x; 1.2880x over previous
//
#include <hip/hip_runtime.h>

#define THREADS 512
#define HW 16384        // H*W per (b,c) row
#define K_SEL 8192u     // k = 0.5 * H * W
#define NB1 2048        // pass-1: abs bits [30:20]
#define NB2 1024        // pass-2: bits [19:10]
#define NB3 1024        // pass-3: bits [9:0]
#define VPT 8           // uint4 per thread (32 floats); THREADS*VPT*4 == HW

static_assert(THREADS * VPT * 4 == HW, "row tiling");

// Two-stage parallel bin search, executed by wave 0 only; result broadcast
// via LDS. Bins ascend in value; finds the bin holding the kRem-th LARGEST
// element and the residual rank within it. ALL cross-lane ops are convergent
// (every lane of wave 0 executes them); only the final LDS write is guarded.
template <int NBINS>
__device__ __forceinline__ void find_bin_wave0(const unsigned* __restrict__ hist,
                                               unsigned kRem, unsigned* __restrict__ bc) {
  constexpr int bpl = NBINS >> 6;             // bins per lane
  const int lane = (int)(threadIdx.x & 63);
  const int base = lane * bpl;
  // Stage 1: bank-rotated chunk sums (conflict-free), suffix-scan over lanes.
  unsigned s = 0;
#pragma unroll
  for (int j = 0; j < bpl; ++j) s += hist[base + ((j + lane) & (bpl - 1))];
  unsigned suf = s;
#pragma unroll
  for (int off = 1; off < 64; off <<= 1) {
    unsigned w = __shfl_down(suf, off);
    if (lane + off < 64) suf += w;
  }
  const unsigned cumAbove = suf - s;
  const bool hit = (cumAbove < kRem) && (kRem <= suf);
  const unsigned long long m = __ballot(hit);
  const int tl = (int)__builtin_ctzll(m);     // unique target chunk
  const unsigned cumTl = __shfl(cumAbove, tl);
  // Stage 2: suffix-scan within the target chunk (lane groups of bpl work
  // redundantly on the same addresses -> LDS broadcast, conflict-free).
  const int j = lane & (bpl - 1);
  const unsigned h = hist[tl * bpl + j];
  unsigned sufc = h;
#pragma unroll
  for (int off = 1; off < 32; off <<= 1) {
    if (off < bpl) {
      unsigned w = __shfl_down(sufc, off);
      if (j + off < bpl) sufc += w;
    }
  }
  const unsigned cumW = sufc - h;
  const bool hit2 = ((cumTl + cumW) < kRem) && (kRem <= cumTl + cumW + h);
  const unsigned long long m2 = __ballot(hit2);
  const int jl = (int)__builtin_ctzll(m2) & (bpl - 1);
  const unsigned kw = __shfl(cumW, jl);       // convergent: all lanes execute
  if (lane == 0) {
    bc[0] = (unsigned)(tl * bpl + jl);
    bc[1] = kRem - cumTl - kw;
  }
}

extern "C" __global__ __launch_bounds__(THREADS, 8)
void sparsify_topk_kernel(const float* __restrict__ x, float* __restrict__ out) {
  __shared__ unsigned h1[NB1];
  __shared__ unsigned h2[NB2];
  __shared__ unsigned h3[NB3];
  __shared__ unsigned bc[2];

  const int t = (int)threadIdx.x;
  const size_t rowOff = (size_t)blockIdx.x * (HW / 4);
  const uint4* src = (const uint4*)x + rowOff;
  uint4*       dst = (uint4*)out + rowOff;

  // Issue the row load first (latency hides under hist zeroing + barrier).
  uint4 v[VPT];
#pragma unroll
  for (int i = 0; i < VPT; ++i) v[i] = src[i * THREADS + t];

  // Zero all hists (each used exactly once per block).
#pragma unroll
  for (int i = 0; i < NB1 / THREADS; ++i) h1[t + i * THREADS] = 0;
#pragma unroll
  for (int i = 0; i < NB2 / THREADS; ++i) h2[t + i * THREADS] = 0;
#pragma unroll
  for (int i = 0; i < NB3 / THREADS; ++i) h3[t + i * THREADS] = 0;
  __syncthreads();

  // P1: bits [30:20] -> h1
#pragma unroll
  for (int i = 0; i < VPT; ++i) {
    atomicAdd(&h1[(v[i].x & 0x7fffffffu) >> 20], 1u);
    atomicAdd(&h1[(v[i].y & 0x7fffffffu) >> 20], 1u);
    atomicAdd(&h1[(v[i].z & 0x7fffffffu) >> 20], 1u);
    atomicAdd(&h1[(v[i].w & 0x7fffffffu) >> 20], 1u);
  }
  __syncthreads();
  if (t < 64) find_bin_wave0<NB1>(h1, K_SEL, bc);
  __syncthreads();
  const unsigned T1 = bc[0];
  unsigned kRem = bc[1];

  // P2: among (a>>20)==T1, bits [19:10] -> h2 (~2% of elements hit)
#pragma unroll
  for (int i = 0; i < VPT; ++i) {
    unsigned a;
    a = v[i].x & 0x7fffffffu; if ((a >> 20) == T1) atomicAdd(&h2[(a >> 10) & (NB2 - 1)], 1u);
    a = v[i].y & 0x7fffffffu; if ((a >> 20) == T1) atomicAdd(&h2[(a >> 10) & (NB2 - 1)], 1u);
    a = v[i].z & 0x7fffffffu; if ((a >> 20) == T1) atomicAdd(&h2[(a >> 10) & (NB2 - 1)], 1u);
    a = v[i].w & 0x7fffffffu; if ((a >> 20) == T1) atomicAdd(&h2[(a >> 10) & (NB2 - 1)], 1u);
  }
  __syncthreads();
  if (t < 64) find_bin_wave0<NB2>(h2, kRem, bc);
  __syncthreads();
  const unsigned pref2 = (T1 << 10) | bc[0];   // == a>>10 of threshold
  kRem = bc[1];

  // P3: among (a>>10)==pref2, bits [9:0] -> h3
#pragma unroll
  for (int i = 0; i < VPT; ++i) {
    unsigned a;
    a = v[i].x & 0x7fffffffu; if ((a >> 10) == pref2) atomicAdd(&h3[a & (NB3 - 1)], 1u);
    a = v[i].y & 0x7fffffffu; if ((a >> 10) == pref2) atomicAdd(&h3[a & (NB3 - 1)], 1u);
    a = v[i].z & 0x7fffffffu; if ((a >> 10) == pref2) atomicAdd(&h3[a & (NB3 - 1)], 1u);
    a = v[i].w & 0x7fffffffu; if ((a >> 10) == pref2) atomicAdd(&h3[a & (NB3 - 1)], 1u);
  }
  __syncthreads();
  if (t < 64) find_bin_wave0<NB3>(h3, kRem, bc);
  __syncthreads();
  const unsigned thr = (pref2 << 10) | bc[0];  // exact k-th largest |x| bits

  // Masked store (>= keeps ties, same as reference).
#pragma unroll
  for (int i = 0; i < VPT; ++i) {
    uint4 w = v[i];
    w.x = ((w.x & 0x7fffffffu) >= thr) ? w.x : 0u;
    w.y = ((w.y & 0x7fffffffu) >= thr) ? w.y : 0u;
    w.z = ((w.z & 0x7fffffffu) >= thr) ? w.z : 0u;
    w.w = ((w.w & 0x7fffffffu) >= thr) ? w.w : 0u;
    dst[i * THREADS + t] = w;
  }
}

extern "C" void kernel_launch(void* const* d_in, const int* in_sizes, int n_in,
                              void* d_out, int out_size, void* d_ws, size_t ws_size,
                              hipStream_t stream) {
  (void)n_in; (void)d_ws; (void)ws_size; (void)out_size;
  const float* x = (const float*)d_in[0];
  float* out = (float*)d_out;
  const int rows = in_sizes[0] / HW;   // 4096
  sparsify_topk_kernel<<<dim3(rows), dim3(THREADS), 0, stream>>>(x, out);
}